// Round 7
// baseline (919.860 us; speedup 1.0000x reference)
//
#include <hip/hip_runtime.h>
#include <stdint.h>

#define NUM_CAP 16
#define DIM_CAP 64
#define BATCH   64
#define N_IN    512
#define D_IN    1024

// ---------------------------------------------------------------------------
// FACTORIZED CAPSULE ROUTING (R13).  Identity (verified algebraically):
//   u_hat[b,j,i,k] = sum_d x[b,j,d] W[d, i*64+k]
//   b_ij  = v_i . u_ij  = x_j . wt_i        where wt_i[d] = sum_k W[d,i*64+k] v_i[k]
//   sum_j c_ij u_ij [k] = s_i . W[:,i*64+k] where s_i[d]  = sum_j c_ij x[b,j,d]
//   iter1: c = 1/16 (uniform) => v1 = squash(colsum_j(x) @ W)  (squash scale-inv)
// So u_hat (64 MB write + 192 MB reads + 68.7 GFLOP bf16 GEMM) is never
// materialized.  All fp32 (matches reference math exactly up to order).
// Budget evidence (R0-R6 closure): timed region contains ~157 us of harness
// poison fills; controllable kernels were prep 33 + gemm 72 + routing 45.
// This pipeline replaces all of it with ~90 us of fp32 streaming/VALU work.
// Workspace: cs8 [512][1024] f32 @0 (2MB); v [64][1024] f32 @2MB;
//            wt [64][16][1024] f32 @4MB; sp [512][16][1024] f32 @8MB (32MB).
// ---------------------------------------------------------------------------

// K1: partial column sums of x over j.  Block bid = b*8+jc sums 64 rows.
// (Same verified structure as the old s1q, on fp32 x.)
__global__ __launch_bounds__(256) void colsum8(
    const float* __restrict__ x, float* __restrict__ cs8) {
  const int t = threadIdx.x;
  const int bid = blockIdx.x;                       // b*8+jc
  const float* p = x + (size_t)bid * 64 * 1024 + t * 4;  // (b*8+jc)*64 = b*512+jc*64
  float4 a = make_float4(0.f, 0.f, 0.f, 0.f);
  #pragma unroll 8
  for (int j = 0; j < 64; ++j, p += 1024) {
    const float4 d = *(const float4*)p;
    a.x += d.x; a.y += d.y; a.z += d.z; a.w += d.w;
  }
  *(float4*)&cs8[(size_t)bid * 1024 + t * 4] = a;
}

// K2: reduce cs8 -> cs (LDS), then v1[n] = squash(sum_d cs[d] W[d][n]).
// Per d-step each wave reads 1KB contiguous of row d (coalesced); cs[d] is a
// same-address LDS broadcast.  Grid 64 (one block per b).
__global__ __launch_bounds__(256) void v_first(
    const float* __restrict__ cs8, const float* __restrict__ W,
    float* __restrict__ v) {
  __shared__ float cs[1024];
  const int t = threadIdx.x, b = blockIdx.x;
  float4 a = make_float4(0.f, 0.f, 0.f, 0.f);
  #pragma unroll
  for (int s = 0; s < 8; ++s) {
    const float4 d = *(const float4*)&cs8[(size_t)(b * 8 + s) * 1024 + t * 4];
    a.x += d.x; a.y += d.y; a.z += d.z; a.w += d.w;
  }
  *(float4*)&cs[t * 4] = a;
  __syncthreads();

  float4 o = make_float4(0.f, 0.f, 0.f, 0.f);
  #pragma unroll 8
  for (int d = 0; d < 1024; ++d) {
    const float c = cs[d];
    const float4 w = *(const float4*)&W[(size_t)d * 1024 + t * 4];
    o.x += c * w.x; o.y += c * w.y; o.z += c * w.z; o.w += c * w.w;
  }
  float ss = o.x * o.x + o.y * o.y + o.z * o.z + o.w * o.w;
  #pragma unroll
  for (int dd = 1; dd < 16; dd <<= 1) ss += __shfl_xor(ss, dd);  // 16 thr = capsule
  const float inv = 1.f / sqrtf(ss + 1e-7f);
  *(float4*)&v[(size_t)b * 1024 + t * 4] =
      make_float4(o.x * inv, o.y * inv, o.z * inv, o.w * inv);
}

// K3a: wt[b][i][d] = sum_k W[d][i*64+k] v[b][i*64+k].
// Block bid = b*16+dblk handles 64 d's; thread (d = t>>2 lane-row, q = t&3)
// computes 4 capsules i=q*4..+3; per lane reads 1KB contiguous of row d.
__global__ __launch_bounds__(256) void wtilde(
    const float* __restrict__ v, const float* __restrict__ W,
    float* __restrict__ wt) {
  __shared__ float vl[1024];
  const int t = threadIdx.x;
  const int b = blockIdx.x >> 4, dblk = blockIdx.x & 15;
  *(float4*)&vl[t * 4] = *(const float4*)&v[(size_t)b * 1024 + t * 4];
  __syncthreads();
  const int d = dblk * 64 + (t >> 2), q = t & 3;
  const float* wrow = W + (size_t)d * 1024 + q * 256;
  #pragma unroll
  for (int ii = 0; ii < 4; ++ii) {
    const int i = q * 4 + ii;
    float dot = 0.f;
    #pragma unroll
    for (int m = 0; m < 16; ++m) {
      const float4 w = *(const float4*)&wrow[ii * 64 + m * 4];
      dot += w.x * vl[i * 64 + m * 4]     + w.y * vl[i * 64 + m * 4 + 1]
           + w.z * vl[i * 64 + m * 4 + 2] + w.w * vl[i * 64 + m * 4 + 3];
    }
    wt[((size_t)b * 16 + i) * 1024 + d] = dot;
  }
}

// K3b: per (b, j-chunk of 64): b2[j][i] = x_j . wt_i  -> softmax over i ->
// sp partial: s_i[d] += c * x_j[d].  Thread (i = t>>4, dr = t&15) owns the
// fixed d-chunk dr*64..+63: wt chunk preloaded to 16 float4 regs; x chunk
// loaded per j (L1-served, 4x i-redundant within wave); dot reduced by
// shfl over the 16 dr-lanes; softmax sum via cv[16] in LDS (double-buffered,
// one barrier/j).  No max-subtract: |b2| <~ 6 (x ~ N(0,1), ||wt|| ~ 1).
__global__ __launch_bounds__(256, 2) void bsoft_s(
    const float* __restrict__ x, const float* __restrict__ wt,
    float* __restrict__ sp) {
  __shared__ float cv[2][16];
  const int t = threadIdx.x;
  const int b = blockIdx.x >> 3, jc = blockIdx.x & 7;
  const int i = t >> 4, dr = t & 15;

  float4 wtr[16];
  {
    const float* wp = wt + ((size_t)b * 16 + i) * 1024 + dr * 64;
    #pragma unroll
    for (int m = 0; m < 16; ++m) wtr[m] = *(const float4*)&wp[m * 4];
  }
  float4 sac[16];
  #pragma unroll
  for (int m = 0; m < 16; ++m) sac[m] = make_float4(0.f, 0.f, 0.f, 0.f);

  const float* xp = x + (size_t)(b * 512 + jc * 64) * 1024 + dr * 64;
  for (int j = 0; j < 64; ++j, xp += 1024) {
    float4 xv[16];
    #pragma unroll
    for (int m = 0; m < 16; ++m) xv[m] = *(const float4*)&xp[m * 4];
    float dot = 0.f;
    #pragma unroll
    for (int m = 0; m < 16; ++m)
      dot += wtr[m].x * xv[m].x + wtr[m].y * xv[m].y
           + wtr[m].z * xv[m].z + wtr[m].w * xv[m].w;
    dot += __shfl_xor(dot, 1);
    dot += __shfl_xor(dot, 2);
    dot += __shfl_xor(dot, 4);
    dot += __shfl_xor(dot, 8);          // full dot over d in all 16 dr-lanes
    const float e = __expf(dot);
    if (dr == 0) cv[j & 1][i] = e;
    __syncthreads();
    float sum = 0.f;
    #pragma unroll
    for (int ii = 0; ii < 16; ++ii) sum += cv[j & 1][ii];
    const float c = e / sum;
    #pragma unroll
    for (int m = 0; m < 16; ++m) {
      sac[m].x += c * xv[m].x; sac[m].y += c * xv[m].y;
      sac[m].z += c * xv[m].z; sac[m].w += c * xv[m].w;
    }
  }
  float* spp = sp + ((size_t)blockIdx.x * 16 + i) * 1024 + dr * 64;
  #pragma unroll
  for (int m = 0; m < 16; ++m) *(float4*)&spp[m * 4] = sac[m];
}

// K3c: reduce the 8 j-chunk partials -> s[16][1024] (LDS, row-padded 1028 so
// the 4 per-wave i-broadcasts hit distinct banks), then
// vout[b][i*64+k] = squash_i(sum_d s[i][d] W[d][i*64+k]).
// Per d-step the block reads the full 4KB row of W (coalesced).  Grid 64.
// Final iteration writes directly to out (same [b][i*64+k] layout).
__global__ __launch_bounds__(256) void red_gemv_squash(
    const float* __restrict__ sp, const float* __restrict__ W,
    float* __restrict__ vout) {
  __shared__ float sl[16 * 1028];
  const int t = threadIdx.x, b = blockIdx.x;
  for (int r = 0; r < 16; ++r) {
    const int idx = r * 1024 + t * 4;     // i = r, d = t*4..+3
    float4 a = make_float4(0.f, 0.f, 0.f, 0.f);
    #pragma unroll
    for (int p = 0; p < 8; ++p) {
      const float4 d = *(const float4*)&sp[(size_t)(b * 8 + p) * 16384 + idx];
      a.x += d.x; a.y += d.y; a.z += d.z; a.w += d.w;
    }
    *(float4*)&sl[r * 1028 + t * 4] = a;
  }
  __syncthreads();

  const int i = t >> 4, kq = t & 15;
  float4 o = make_float4(0.f, 0.f, 0.f, 0.f);
  #pragma unroll 8
  for (int d = 0; d < 1024; ++d) {
    const float s = sl[i * 1028 + d];
    const float4 w = *(const float4*)&W[(size_t)d * 1024 + i * 64 + kq * 4];
    o.x += s * w.x; o.y += s * w.y; o.z += s * w.z; o.w += s * w.w;
  }
  float ss = o.x * o.x + o.y * o.y + o.z * o.z + o.w * o.w;
  #pragma unroll
  for (int dd = 1; dd < 16; dd <<= 1) ss += __shfl_xor(ss, dd);  // capsule group
  const float inv = 1.f / sqrtf(ss + 1e-7f);
  // n = i*64 + kq*4 = t*4 -> coalesced
  *(float4*)&vout[(size_t)b * 1024 + t * 4] =
      make_float4(o.x * inv, o.y * inv, o.z * inv, o.w * inv);
}

// ---------------------------------------------------------------------------
extern "C" void kernel_launch(void* const* d_in, const int* in_sizes, int n_in,
                              void* d_out, int out_size, void* d_ws, size_t ws_size,
                              hipStream_t stream) {
  const float* x = (const float*)d_in[0];   // [64][512][1024] fp32
  const float* W = (const float*)d_in[1];   // [1][1024][1024] fp32 (W[0])
  float* out = (float*)d_out;               // [64][16][64] fp32 == [b][1024]

  char* ws = (char*)d_ws;
  float* cs8 = (float*)ws;                          // 0..2 MB   [512][1024]
  float* v   = (float*)(ws + (size_t)(2 << 20));    // 2..3 MB   [64][1024]
  float* wt  = (float*)(ws + (size_t)(4 << 20));    // 4..8 MB   [64][16][1024]
  float* sp  = (float*)(ws + (size_t)(8 << 20));    // 8..40 MB  [512][16][1024]

  // iter 1 (uniform c): v1 = squash(colsum(x) @ W)
  colsum8<<<512, 256, 0, stream>>>(x, cs8);
  v_first<<<64, 256, 0, stream>>>(cs8, W, v);
  // iter 2
  wtilde<<<1024, 256, 0, stream>>>(v, W, wt);
  bsoft_s<<<512, 256, 0, stream>>>(x, wt, sp);
  red_gemv_squash<<<64, 256, 0, stream>>>(sp, W, v);
  // iter 3 -> output
  wtilde<<<1024, 256, 0, stream>>>(v, W, wt);
  bsoft_s<<<512, 256, 0, stream>>>(x, wt, sp);
  red_gemv_squash<<<64, 256, 0, stream>>>(sp, W, out);
}

// Round 8
// 685.383 us; speedup vs baseline: 1.3421x; 1.3421x over previous
//
#include <hip/hip_runtime.h>
#include <stdint.h>

#define NUM_CAP 16
#define DIM_CAP 64
#define BATCH   64
#define N_IN    512
#define D_IN    1024

// ---------------------------------------------------------------------------
// FACTORIZED CAPSULE ROUTING v2 (R14).  Identity (R13-verified, absmax 1e-3):
//   b_ij  = x_j . wt_i          wt_i[d]  = sum_k W[d,i*64+k] v_i[k]
//   sum_j c_ij u_ij [k] = s_i . W[:,i*64+k],  s_i[d] = sum_j c_ij x[b,j,d]
//   iter1: c uniform => v1 = squash(colsum_j(x) @ W)
// R13 measured: right algebra, wrong decomposition — bsoft_s 248 us/call
// (VALUBusy 12.8%: per-j barrier + 16x-redundant x loads + shfl chain
// serialized ~9K cyc/j); grid-64 GEMVs latency-bound.  v2 re-decomposes:
//   bsoft2: 3 barriers total, x read 2x/block, dots via end-of-loop shfl.
//   gemv_part/fin: split (8b x 16dq) x 256thr; W read once per block slice
//     (amplification 64x -> 8x), dd loop-uniform => coalesced row reads.
//   wtilde2: 8 b per block via LDS-staged v (W traffic 256 -> 32 MB).
// Workspace: cs8 @0 (2MB), v @2MB, wt @4MB (4MB), sp @8MB (32MB), po @40MB.
// ---------------------------------------------------------------------------

// K1: partial column sums of x over j.  Block bid = b*8+jc sums 64 rows.
__global__ __launch_bounds__(256) void colsum8(
    const float* __restrict__ x, float* __restrict__ cs8) {
  const int t = threadIdx.x;
  const float* p = x + (size_t)blockIdx.x * 64 * 1024 + t * 4;
  float4 a = make_float4(0.f, 0.f, 0.f, 0.f);
  #pragma unroll 8
  for (int j = 0; j < 64; ++j, p += 1024) {
    const float4 d = *(const float4*)p;
    a.x += d.x; a.y += d.y; a.z += d.z; a.w += d.w;
  }
  *(float4*)&cs8[(size_t)blockIdx.x * 1024 + t * 4] = a;
}

// K2: GEMV partial.  Grid 128 = bg(8) x dq(16); block handles 8 b's and 64
// d's.  Stage S[b8][i][dd] in LDS (mode 0: S = sum_p cs8, i-uniform;
// mode 1: S = sum_p sp).  Then po[b][dq][i*64+k] = sum_dd S*W: per dd the
// wave reads 1KB contiguous of row dq*64+dd (dd uniform => coalesced), 8
// f4-FMA into o[8].
__global__ __launch_bounds__(256) void gemv_part(
    const float* __restrict__ src, const float* __restrict__ W,
    float* __restrict__ po, const int mode) {
  __shared__ float sl[8 * 16 * 68];  // [b8][i][dd] stride 68
  const int t = threadIdx.x;
  const int bg = blockIdx.x >> 4, dq = blockIdx.x & 15;
  const int i = t >> 4, dd4 = (t & 15) * 4;

  #pragma unroll
  for (int b8 = 0; b8 < 8; ++b8) {
    float4 a = make_float4(0.f, 0.f, 0.f, 0.f);
    if (mode == 0) {
      #pragma unroll
      for (int p = 0; p < 8; ++p) {
        const float4 d = *(const float4*)&src[(size_t)((bg * 8 + b8) * 8 + p) * 1024 + dq * 64 + dd4];
        a.x += d.x; a.y += d.y; a.z += d.z; a.w += d.w;
      }
    } else {
      #pragma unroll
      for (int p = 0; p < 8; ++p) {
        const float4 d = *(const float4*)&src[(size_t)((bg * 8 + b8) * 8 + p) * 16384 + i * 1024 + dq * 64 + dd4];
        a.x += d.x; a.y += d.y; a.z += d.z; a.w += d.w;
      }
    }
    *(float4*)&sl[(b8 * 16 + i) * 68 + dd4] = a;
  }
  __syncthreads();

  const int kq = t & 15;
  const float* wp = W + (size_t)(dq * 64) * 1024 + i * 64 + kq * 4;
  float4 o[8];
  #pragma unroll
  for (int b8 = 0; b8 < 8; ++b8) o[b8] = make_float4(0.f, 0.f, 0.f, 0.f);
  #pragma unroll 8
  for (int dd = 0; dd < 64; ++dd) {
    const float4 w = *(const float4*)&wp[(size_t)dd * 1024];
    #pragma unroll
    for (int b8 = 0; b8 < 8; ++b8) {
      const float s = sl[(b8 * 16 + i) * 68 + dd];
      o[b8].x += s * w.x; o[b8].y += s * w.y; o[b8].z += s * w.z; o[b8].w += s * w.w;
    }
  }
  #pragma unroll
  for (int b8 = 0; b8 < 8; ++b8)
    *(float4*)&po[((size_t)(bg * 8 + b8) * 16 + dq) * 1024 + t * 4] = o[b8];
}

// K3: reduce 16 dq-partials + squash.  Grid 64 (b), thread t covers n=t*4.
__global__ __launch_bounds__(256) void gemv_fin(
    const float* __restrict__ po, float* __restrict__ dst) {
  const int t = threadIdx.x, b = blockIdx.x;
  float4 o = make_float4(0.f, 0.f, 0.f, 0.f);
  #pragma unroll
  for (int dq = 0; dq < 16; ++dq) {
    const float4 p = *(const float4*)&po[((size_t)b * 16 + dq) * 1024 + t * 4];
    o.x += p.x; o.y += p.y; o.z += p.z; o.w += p.w;
  }
  float ss = o.x * o.x + o.y * o.y + o.z * o.z + o.w * o.w;
  #pragma unroll
  for (int d = 1; d < 16; d <<= 1) ss += __shfl_xor(ss, d);  // 16 thr = capsule
  const float inv = 1.f / sqrtf(ss + 1e-7f);
  *(float4*)&dst[(size_t)b * 1024 + t * 4] =
      make_float4(o.x * inv, o.y * inv, o.z * inv, o.w * inv);
}

// K4: wt[b][i][d] = sum_k W[d][i*64+k] v[b][i*64+k].  Grid 128 = bg(8) x
// dblk(16); v for 8 b's staged in LDS (broadcast reads); thread (d=t>>2,
// q=t&3) streams its contiguous 1KB W quarter once, 8 b accumulators.
__global__ __launch_bounds__(256) void wtilde2(
    const float* __restrict__ v, const float* __restrict__ W,
    float* __restrict__ wt) {
  __shared__ float vl[8][1024];
  const int t = threadIdx.x;
  const int bg = blockIdx.x >> 4, dblk = blockIdx.x & 15;
  #pragma unroll
  for (int b8 = 0; b8 < 8; ++b8)
    *(float4*)&vl[b8][t * 4] = *(const float4*)&v[(size_t)(bg * 8 + b8) * 1024 + t * 4];
  __syncthreads();

  const int d = dblk * 64 + (t >> 2), q = t & 3;
  const float* wrow = W + (size_t)d * 1024 + q * 256;
  float acc[4][8];
  #pragma unroll
  for (int ii = 0; ii < 4; ++ii)
    #pragma unroll
    for (int b8 = 0; b8 < 8; ++b8) acc[ii][b8] = 0.f;

  #pragma unroll
  for (int ii = 0; ii < 4; ++ii)
    #pragma unroll
    for (int m = 0; m < 16; ++m) {
      const float4 w = *(const float4*)&wrow[ii * 64 + m * 4];
      const int vo = q * 256 + ii * 64 + m * 4;
      #pragma unroll
      for (int b8 = 0; b8 < 8; ++b8)
        acc[ii][b8] += w.x * vl[b8][vo] + w.y * vl[b8][vo + 1]
                     + w.z * vl[b8][vo + 2] + w.w * vl[b8][vo + 3];
    }
  #pragma unroll
  for (int ii = 0; ii < 4; ++ii)
    #pragma unroll
    for (int b8 = 0; b8 < 8; ++b8)
      wt[((size_t)(bg * 8 + b8) * 16 + q * 4 + ii) * 1024 + d] = acc[ii][b8];
}

// K5: fused b-dot + softmax + s-accumulate, 3 barriers total.
// Block (b, jc): 64 j's.  LDS: wt[16][1024] (64KB) + b2l[64][20].
// Pass 1: thread (jg=t>>4, ds=t&15): 4 j x 16 i partial dots over
//   d in {ds*4+64m}; x coalesced 1x; wt LDS reads 16B-spread (2-way free);
//   end-of-loop shfl_xor(1,2,4,8) over ds completes dots; ds==0 writes b2l.
// Softmax: thread (jj=t>>2, q=t&3): 4 e-values, 2-shfl row sum, c in-place.
// Pass 2: thread owns d=t*4..+3 for ALL 16 i (x read once per block);
//   c[j][i] via 4 same-address f4 broadcasts; 16 f4-FMA/j.
__global__ __launch_bounds__(256, 2) void bsoft2(
    const float* __restrict__ x, const float* __restrict__ wt,
    float* __restrict__ sp) {
  __shared__ float wtl[16 * 1024];
  __shared__ float b2l[64 * 20];
  const int t = threadIdx.x;
  const int b = blockIdx.x >> 3, jc = blockIdx.x & 7;

  #pragma unroll
  for (int r = 0; r < 16; ++r)
    *(float4*)&wtl[r * 1024 + t * 4] =
        *(const float4*)&wt[((size_t)b * 16 + r) * 1024 + t * 4];
  __syncthreads();

  // ---- pass 1: b2[j][i] = x_j . wt_i ----
  const int jg = t >> 4, ds = t & 15;
  float acc[16][4];
  #pragma unroll
  for (int i = 0; i < 16; ++i)
    #pragma unroll
    for (int jl = 0; jl < 4; ++jl) acc[i][jl] = 0.f;

  const float* xp = x + (size_t)(b * 512 + jc * 64 + jg * 4) * 1024 + ds * 4;
  #pragma unroll
  for (int m = 0; m < 16; ++m) {
    float4 xv[4];
    #pragma unroll
    for (int jl = 0; jl < 4; ++jl)
      xv[jl] = *(const float4*)(xp + (size_t)jl * 1024 + m * 64);
    #pragma unroll
    for (int iq = 0; iq < 4; ++iq) {
      float4 wv[4];
      #pragma unroll
      for (int ii = 0; ii < 4; ++ii)
        wv[ii] = *(const float4*)&wtl[(iq * 4 + ii) * 1024 + ds * 4 + m * 64];
      #pragma unroll
      for (int ii = 0; ii < 4; ++ii)
        #pragma unroll
        for (int jl = 0; jl < 4; ++jl)
          acc[iq * 4 + ii][jl] += wv[ii].x * xv[jl].x + wv[ii].y * xv[jl].y
                                + wv[ii].z * xv[jl].z + wv[ii].w * xv[jl].w;
    }
  }
  #pragma unroll
  for (int i = 0; i < 16; ++i)
    #pragma unroll
    for (int jl = 0; jl < 4; ++jl) {
      float s = acc[i][jl];
      s += __shfl_xor(s, 1); s += __shfl_xor(s, 2);
      s += __shfl_xor(s, 4); s += __shfl_xor(s, 8);
      acc[i][jl] = s;
    }
  if (ds == 0) {
    #pragma unroll
    for (int jl = 0; jl < 4; ++jl)
      #pragma unroll
      for (int i = 0; i < 16; ++i) b2l[(jg * 4 + jl) * 20 + i] = acc[i][jl];
  }
  __syncthreads();

  // ---- softmax over i (|b2| <~ 8: no max-subtract; R13-verified) ----
  {
    const int jj = t >> 2, q = t & 3;
    float e[4];
    float ps = 0.f;
    #pragma unroll
    for (int ii = 0; ii < 4; ++ii) {
      e[ii] = __expf(b2l[jj * 20 + q * 4 + ii]);
      ps += e[ii];
    }
    ps += __shfl_xor(ps, 1);
    ps += __shfl_xor(ps, 2);
    const float rs = 1.f / ps;
    #pragma unroll
    for (int ii = 0; ii < 4; ++ii) b2l[jj * 20 + q * 4 + ii] = e[ii] * rs;
  }
  __syncthreads();

  // ---- pass 2: s[i][d] = sum_j c[j][i] x[j][d] ----
  float4 sac[16];
  #pragma unroll
  for (int i = 0; i < 16; ++i) sac[i] = make_float4(0.f, 0.f, 0.f, 0.f);
  const float* xq = x + (size_t)(b * 512 + jc * 64) * 1024 + t * 4;
  for (int j = 0; j < 64; ++j, xq += 1024) {
    const float4 xv = *(const float4*)xq;
    #pragma unroll
    for (int iq = 0; iq < 4; ++iq) {
      const float4 cv = *(const float4*)&b2l[j * 20 + iq * 4];
      sac[iq * 4 + 0].x += cv.x * xv.x; sac[iq * 4 + 0].y += cv.x * xv.y;
      sac[iq * 4 + 0].z += cv.x * xv.z; sac[iq * 4 + 0].w += cv.x * xv.w;
      sac[iq * 4 + 1].x += cv.y * xv.x; sac[iq * 4 + 1].y += cv.y * xv.y;
      sac[iq * 4 + 1].z += cv.y * xv.z; sac[iq * 4 + 1].w += cv.y * xv.w;
      sac[iq * 4 + 2].x += cv.z * xv.x; sac[iq * 4 + 2].y += cv.z * xv.y;
      sac[iq * 4 + 2].z += cv.z * xv.z; sac[iq * 4 + 2].w += cv.z * xv.w;
      sac[iq * 4 + 3].x += cv.w * xv.x; sac[iq * 4 + 3].y += cv.w * xv.y;
      sac[iq * 4 + 3].z += cv.w * xv.z; sac[iq * 4 + 3].w += cv.w * xv.w;
    }
  }
  #pragma unroll
  for (int i = 0; i < 16; ++i)
    *(float4*)&sp[((size_t)blockIdx.x * 16 + i) * 1024 + t * 4] = sac[i];
}

// ---------------------------------------------------------------------------
extern "C" void kernel_launch(void* const* d_in, const int* in_sizes, int n_in,
                              void* d_out, int out_size, void* d_ws, size_t ws_size,
                              hipStream_t stream) {
  const float* x = (const float*)d_in[0];   // [64][512][1024] fp32
  const float* W = (const float*)d_in[1];   // [1][1024][1024] fp32 (W[0])
  float* out = (float*)d_out;               // [64][16][64] fp32 == [b][1024]

  char* ws = (char*)d_ws;
  float* cs8 = (float*)ws;                          // 0..2 MB   [512][1024]
  float* v   = (float*)(ws + (size_t)(2 << 20));    // 2..3 MB   [64][1024]
  float* wt  = (float*)(ws + (size_t)(4 << 20));    // 4..8 MB   [64][16][1024]
  float* sp  = (float*)(ws + (size_t)(8 << 20));    // 8..40 MB  [512][16][1024]
  float* po  = (float*)(ws + (size_t)(40 << 20));   // 40..44 MB [64][16][1024]

  // iter 1 (uniform c): v1 = squash(colsum(x) @ W)
  colsum8<<<512, 256, 0, stream>>>(x, cs8);
  gemv_part<<<128, 256, 0, stream>>>(cs8, W, po, 0);
  gemv_fin<<<64, 256, 0, stream>>>(po, v);
  // iter 2
  wtilde2<<<128, 256, 0, stream>>>(v, W, wt);
  bsoft2<<<512, 256, 0, stream>>>(x, wt, sp);
  gemv_part<<<128, 256, 0, stream>>>(sp, W, po, 1);
  gemv_fin<<<64, 256, 0, stream>>>(po, v);
  // iter 3 -> output
  wtilde2<<<128, 256, 0, stream>>>(v, W, wt);
  bsoft2<<<512, 256, 0, stream>>>(x, wt, sp);
  gemv_part<<<128, 256, 0, stream>>>(sp, W, po, 1);
  gemv_fin<<<64, 256, 0, stream>>>(po, out);
}

// Round 11
// 383.986 us; speedup vs baseline: 2.3956x; 1.7849x over previous
//
#include <hip/hip_runtime.h>
#include <stdint.h>

#define NUM_CAP 16
#define DIM_CAP 64
#define BATCH   64
#define N_IN    512
#define D_IN    1024

// ---------------------------------------------------------------------------
// FACTORIZED CAPSULE ROUTING v3 (R15; 3rd submission — R16/R17 were broker
// "container failed twice" infra errors, not kernel outcomes; source is
// byte-identical to R15 modulo this header).
// Identity (R13-verified, absmax 1e-3):
//   b_ij  = x_j . wt_i          wt_i[d]  = sum_k W[d,i*64+k] v_i[k]
//   sum_j c_ij u_ij [k] = s_i . W[:,i*64+k],  s_i[d] = sum_j c_ij x[b,j,d]
//   iter1: c uniform => v1 = squash(colsum_j(x) @ W)
// R14 measured: bsoft2 212 us/call with WRITE_SIZE 298 MB vs 32 expected ->
// SCRATCH SPILLS (pass-1 acc[16][4]+xv[4]+wv[4] ~ 140 live > 128 VGPR).
// v3: pass-1 re-mapped to (jg=32 x ds=8, 2 j/thread): acc[16][2]=32 regs,
// live state ~70 -> no spill.  wv reads become 8-address x 8-lane broadcast
// (conflict-free).  Everything else identical to R14.
// Workspace: cs8 @0 (2MB), v @2MB, wt @4MB (4MB), sp @8MB (32MB), po @40MB.
// ---------------------------------------------------------------------------

// K1: partial column sums of x over j.  Block bid = b*8+jc sums 64 rows.
__global__ __launch_bounds__(256) void colsum8(
    const float* __restrict__ x, float* __restrict__ cs8) {
  const int t = threadIdx.x;
  const float* p = x + (size_t)blockIdx.x * 64 * 1024 + t * 4;
  float4 a = make_float4(0.f, 0.f, 0.f, 0.f);
  #pragma unroll 8
  for (int j = 0; j < 64; ++j, p += 1024) {
    const float4 d = *(const float4*)p;
    a.x += d.x; a.y += d.y; a.z += d.z; a.w += d.w;
  }
  *(float4*)&cs8[(size_t)blockIdx.x * 1024 + t * 4] = a;
}

// K2: GEMV partial.  Grid 128 = bg(8) x dq(16); block handles 8 b's and 64
// d's.  Stage S[b8][i][dd] in LDS (mode 0: S = sum_p cs8, i-uniform;
// mode 1: S = sum_p sp).  po[b][dq][i*64+k] = sum_dd S*W (dd loop-uniform
// => coalesced full-row reads of W).
__global__ __launch_bounds__(256) void gemv_part(
    const float* __restrict__ src, const float* __restrict__ W,
    float* __restrict__ po, const int mode) {
  __shared__ float sl[8 * 16 * 68];  // [b8][i][dd] stride 68
  const int t = threadIdx.x;
  const int bg = blockIdx.x >> 4, dq = blockIdx.x & 15;
  const int i = t >> 4, dd4 = (t & 15) * 4;

  #pragma unroll
  for (int b8 = 0; b8 < 8; ++b8) {
    float4 a = make_float4(0.f, 0.f, 0.f, 0.f);
    if (mode == 0) {
      #pragma unroll
      for (int p = 0; p < 8; ++p) {
        const float4 d = *(const float4*)&src[(size_t)((bg * 8 + b8) * 8 + p) * 1024 + dq * 64 + dd4];
        a.x += d.x; a.y += d.y; a.z += d.z; a.w += d.w;
      }
    } else {
      #pragma unroll
      for (int p = 0; p < 8; ++p) {
        const float4 d = *(const float4*)&src[(size_t)((bg * 8 + b8) * 8 + p) * 16384 + i * 1024 + dq * 64 + dd4];
        a.x += d.x; a.y += d.y; a.z += d.z; a.w += d.w;
      }
    }
    *(float4*)&sl[(b8 * 16 + i) * 68 + dd4] = a;
  }
  __syncthreads();

  const int kq = t & 15;
  const float* wp = W + (size_t)(dq * 64) * 1024 + i * 64 + kq * 4;
  float4 o[8];
  #pragma unroll
  for (int b8 = 0; b8 < 8; ++b8) o[b8] = make_float4(0.f, 0.f, 0.f, 0.f);
  #pragma unroll 8
  for (int dd = 0; dd < 64; ++dd) {
    const float4 w = *(const float4*)&wp[(size_t)dd * 1024];
    #pragma unroll
    for (int b8 = 0; b8 < 8; ++b8) {
      const float s = sl[(b8 * 16 + i) * 68 + dd];
      o[b8].x += s * w.x; o[b8].y += s * w.y; o[b8].z += s * w.z; o[b8].w += s * w.w;
    }
  }
  #pragma unroll
  for (int b8 = 0; b8 < 8; ++b8)
    *(float4*)&po[((size_t)(bg * 8 + b8) * 16 + dq) * 1024 + t * 4] = o[b8];
}

// K3: reduce 16 dq-partials + squash.  Grid 64 (b), thread t covers n=t*4.
__global__ __launch_bounds__(256) void gemv_fin(
    const float* __restrict__ po, float* __restrict__ dst) {
  const int t = threadIdx.x, b = blockIdx.x;
  float4 o = make_float4(0.f, 0.f, 0.f, 0.f);
  #pragma unroll
  for (int dq = 0; dq < 16; ++dq) {
    const float4 p = *(const float4*)&po[((size_t)b * 16 + dq) * 1024 + t * 4];
    o.x += p.x; o.y += p.y; o.z += p.z; o.w += p.w;
  }
  float ss = o.x * o.x + o.y * o.y + o.z * o.z + o.w * o.w;
  #pragma unroll
  for (int d = 1; d < 16; d <<= 1) ss += __shfl_xor(ss, d);  // 16 thr = capsule
  const float inv = 1.f / sqrtf(ss + 1e-7f);
  *(float4*)&dst[(size_t)b * 1024 + t * 4] =
      make_float4(o.x * inv, o.y * inv, o.z * inv, o.w * inv);
}

// K4: wt[b][i][d] = sum_k W[d][i*64+k] v[b][i*64+k].  Grid 128 = bg(8) x
// dblk(16); v for 8 b's staged in LDS (broadcast reads); thread (d=t>>2,
// q=t&3) streams its contiguous 1KB W quarter once, 8 b accumulators.
__global__ __launch_bounds__(256) void wtilde2(
    const float* __restrict__ v, const float* __restrict__ W,
    float* __restrict__ wt) {
  __shared__ float vl[8][1024];
  const int t = threadIdx.x;
  const int bg = blockIdx.x >> 4, dblk = blockIdx.x & 15;
  #pragma unroll
  for (int b8 = 0; b8 < 8; ++b8)
    *(float4*)&vl[b8][t * 4] = *(const float4*)&v[(size_t)(bg * 8 + b8) * 1024 + t * 4];
  __syncthreads();

  const int d = dblk * 64 + (t >> 2), q = t & 3;
  const float* wrow = W + (size_t)d * 1024 + q * 256;
  float acc[4][8];
  #pragma unroll
  for (int ii = 0; ii < 4; ++ii)
    #pragma unroll
    for (int b8 = 0; b8 < 8; ++b8) acc[ii][b8] = 0.f;

  #pragma unroll
  for (int ii = 0; ii < 4; ++ii)
    #pragma unroll
    for (int m = 0; m < 16; ++m) {
      const float4 w = *(const float4*)&wrow[ii * 64 + m * 4];
      const int vo = q * 256 + ii * 64 + m * 4;
      #pragma unroll
      for (int b8 = 0; b8 < 8; ++b8)
        acc[ii][b8] += w.x * vl[b8][vo] + w.y * vl[b8][vo + 1]
                     + w.z * vl[b8][vo + 2] + w.w * vl[b8][vo + 3];
    }
  #pragma unroll
  for (int ii = 0; ii < 4; ++ii)
    #pragma unroll
    for (int b8 = 0; b8 < 8; ++b8)
      wt[((size_t)(bg * 8 + b8) * 16 + q * 4 + ii) * 1024 + d] = acc[ii][b8];
}

// K5: fused b-dot + softmax + s-accumulate, 3 barriers total.
// Block (b, jc): 64 j's.  LDS: wt[16][1024] (64KB) + b2l[64][20].
// Pass 1 (R15 remap): thread (jg=t>>3, ds=t&7) owns j=jg*2+{0,1}; partial
//   dots over d in {ds*4 + 32m}, m<32; acc[16][2]=32 regs (no spill);
//   shfl_xor(1,2,4) over the 8 ds-lanes completes dots; ds==0 writes b2l.
//   wv LDS reads: 8 distinct f4 x 8-lane broadcast = conflict-free.
// Softmax: thread (jj=t>>2, q=t&3): 4 e-values, 2-shfl row sum, c in-place.
// Pass 2: thread owns d=t*4..+3 for ALL 16 i (x read once); c[j][i] via 4
//   same-address f4 broadcasts; 16 f4-FMA/j.
__global__ __launch_bounds__(256, 2) void bsoft3(
    const float* __restrict__ x, const float* __restrict__ wt,
    float* __restrict__ sp) {
  __shared__ float wtl[16 * 1024];
  __shared__ float b2l[64 * 20];
  const int t = threadIdx.x;
  const int b = blockIdx.x >> 3, jc = blockIdx.x & 7;

  #pragma unroll
  for (int r = 0; r < 16; ++r)
    *(float4*)&wtl[r * 1024 + t * 4] =
        *(const float4*)&wt[((size_t)b * 16 + r) * 1024 + t * 4];
  __syncthreads();

  // ---- pass 1: b2[j][i] = x_j . wt_i ----
  const int jg = t >> 3, ds = t & 7;
  float acc[16][2];
  #pragma unroll
  for (int i = 0; i < 16; ++i) { acc[i][0] = 0.f; acc[i][1] = 0.f; }

  const float* xp = x + (size_t)(b * 512 + jc * 64 + jg * 2) * 1024 + ds * 4;
  #pragma unroll 4
  for (int m = 0; m < 32; ++m) {
    const float4 xv0 = *(const float4*)(xp + m * 32);
    const float4 xv1 = *(const float4*)(xp + 1024 + m * 32);
    #pragma unroll
    for (int ii = 0; ii < 16; ++ii) {
      const float4 w = *(const float4*)&wtl[ii * 1024 + ds * 4 + m * 32];
      acc[ii][0] += w.x * xv0.x + w.y * xv0.y + w.z * xv0.z + w.w * xv0.w;
      acc[ii][1] += w.x * xv1.x + w.y * xv1.y + w.z * xv1.z + w.w * xv1.w;
    }
  }
  #pragma unroll
  for (int i = 0; i < 16; ++i)
    #pragma unroll
    for (int jl = 0; jl < 2; ++jl) {
      float s = acc[i][jl];
      s += __shfl_xor(s, 1); s += __shfl_xor(s, 2); s += __shfl_xor(s, 4);
      acc[i][jl] = s;
    }
  if (ds == 0) {
    #pragma unroll
    for (int jl = 0; jl < 2; ++jl)
      #pragma unroll
      for (int i = 0; i < 16; ++i) b2l[(jg * 2 + jl) * 20 + i] = acc[i][jl];
  }
  __syncthreads();

  // ---- softmax over i (|b2| <~ 8: no max-subtract; R13-verified) ----
  {
    const int jj = t >> 2, q = t & 3;
    float e[4];
    float ps = 0.f;
    #pragma unroll
    for (int ii = 0; ii < 4; ++ii) {
      e[ii] = __expf(b2l[jj * 20 + q * 4 + ii]);
      ps += e[ii];
    }
    ps += __shfl_xor(ps, 1);
    ps += __shfl_xor(ps, 2);
    const float rs = 1.f / ps;
    #pragma unroll
    for (int ii = 0; ii < 4; ++ii) b2l[jj * 20 + q * 4 + ii] = e[ii] * rs;
  }
  __syncthreads();

  // ---- pass 2: s[i][d] = sum_j c[j][i] x[j][d] ----
  float4 sac[16];
  #pragma unroll
  for (int i = 0; i < 16; ++i) sac[i] = make_float4(0.f, 0.f, 0.f, 0.f);
  const float* xq = x + (size_t)(b * 512 + jc * 64) * 1024 + t * 4;
  for (int j = 0; j < 64; ++j, xq += 1024) {
    const float4 xv = *(const float4*)xq;
    #pragma unroll
    for (int iq = 0; iq < 4; ++iq) {
      const float4 cv = *(const float4*)&b2l[j * 20 + iq * 4];
      sac[iq * 4 + 0].x += cv.x * xv.x; sac[iq * 4 + 0].y += cv.x * xv.y;
      sac[iq * 4 + 0].z += cv.x * xv.z; sac[iq * 4 + 0].w += cv.x * xv.w;
      sac[iq * 4 + 1].x += cv.y * xv.x; sac[iq * 4 + 1].y += cv.y * xv.y;
      sac[iq * 4 + 1].z += cv.y * xv.z; sac[iq * 4 + 1].w += cv.y * xv.w;
      sac[iq * 4 + 2].x += cv.z * xv.x; sac[iq * 4 + 2].y += cv.z * xv.y;
      sac[iq * 4 + 2].z += cv.z * xv.z; sac[iq * 4 + 2].w += cv.z * xv.w;
      sac[iq * 4 + 3].x += cv.w * xv.x; sac[iq * 4 + 3].y += cv.w * xv.y;
      sac[iq * 4 + 3].z += cv.w * xv.z; sac[iq * 4 + 3].w += cv.w * xv.w;
    }
  }
  #pragma unroll
  for (int i = 0; i < 16; ++i)
    *(float4*)&sp[((size_t)blockIdx.x * 16 + i) * 1024 + t * 4] = sac[i];
}

// ---------------------------------------------------------------------------
extern "C" void kernel_launch(void* const* d_in, const int* in_sizes, int n_in,
                              void* d_out, int out_size, void* d_ws, size_t ws_size,
                              hipStream_t stream) {
  const float* x = (const float*)d_in[0];   // [64][512][1024] fp32
  const float* W = (const float*)d_in[1];   // [1][1024][1024] fp32 (W[0])
  float* out = (float*)d_out;               // [64][16][64] fp32 == [b][1024]

  char* ws = (char*)d_ws;
  float* cs8 = (float*)ws;                          // 0..2 MB   [512][1024]
  float* v   = (float*)(ws + (size_t)(2 << 20));    // 2..3 MB   [64][1024]
  float* wt  = (float*)(ws + (size_t)(4 << 20));    // 4..8 MB   [64][16][1024]
  float* sp  = (float*)(ws + (size_t)(8 << 20));    // 8..40 MB  [512][16][1024]
  float* po  = (float*)(ws + (size_t)(40 << 20));   // 40..44 MB [64][16][1024]

  // iter 1 (uniform c): v1 = squash(colsum(x) @ W)
  colsum8<<<512, 256, 0, stream>>>(x, cs8);
  gemv_part<<<128, 256, 0, stream>>>(cs8, W, po, 0);
  gemv_fin<<<64, 256, 0, stream>>>(po, v);
  // iter 2
  wtilde2<<<128, 256, 0, stream>>>(v, W, wt);
  bsoft3<<<512, 256, 0, stream>>>(x, wt, sp);
  gemv_part<<<128, 256, 0, stream>>>(sp, W, po, 1);
  gemv_fin<<<64, 256, 0, stream>>>(po, v);
  // iter 3 -> output
  wtilde2<<<128, 256, 0, stream>>>(v, W, wt);
  bsoft3<<<512, 256, 0, stream>>>(x, wt, sp);
  gemv_part<<<128, 256, 0, stream>>>(sp, W, po, 1);
  gemv_fin<<<64, 256, 0, stream>>>(po, out);
}